// Round 2
// baseline (566.790 us; speedup 1.0000x reference)
//
#include <hip/hip_runtime.h>

// L2LGD2: learned-optimizer update step (GRUCell hid=8 + Dense(1) per row).
//
// R5: packed-FP32 rewrite, take 2. R4 failed to compile: v_pk_fma_f32 is
// VOP3P — ALL operands must be 64-bit VGPR pairs; a scalar float src1 ("v89")
// is an invalid operand. Fix: broadcast values are packed PAIRWISE and the
// half is chosen with op_sel:
//   lo-broadcast: op_sel:[0,0,0] op_sel_hi:[1,0,1]  (src1.lo feeds both halves)
//   hi-broadcast: op_sel:[0,1,0] op_sel_hi:[1,1,1]  (src1.hi feeds both halves)
// ds_swizzle of hv.x/hv.y lands h[2q],h[2q+1] in one pair naturally, so the
// 8 h-broadcasts cost 8 swizzles into 4 pairs, zero extra movs.
//
// Layout: 4 lanes per row, lane m owns packed column pair {2m, 2m+1}.
// rocprof R3: VALUBusy ~74% @ 29% HBM BW -> VALU-issue-bound, 2.7x above the
// ~72us memory floor. Packed FMAs halve the dominant issue-slot term.
//
// Carried from R3: __launch_bounds__(256,4) (128-VGPR budget) + PIN of every
// loop-invariant + asm memory barrier so the ~69 weight VGPRs cannot be
// re-materialized inside the loop.

typedef float f32x2 __attribute__((ext_vector_type(2)));

#define SWZ(x, imm) __int_as_float(__builtin_amdgcn_ds_swizzle(__float_as_int(x), (imm)))
#define PIN(x) asm volatile("" : "+v"(x))

// d += a * broadcast(b.lo)   [all operands f32x2 register pairs]
#define PK_FMA_BLO(d, a, bp) \
    asm("v_pk_fma_f32 %0, %1, %2, %0 op_sel:[0,0,0] op_sel_hi:[1,0,1]" \
        : "+v"(d) : "v"(a), "v"(bp))
// d += a * broadcast(b.hi)
#define PK_FMA_BHI(d, a, bp) \
    asm("v_pk_fma_f32 %0, %1, %2, %0 op_sel:[0,1,0] op_sel_hi:[1,1,1]" \
        : "+v"(d) : "v"(a), "v"(bp))
// d = a * broadcast(b.lo) + c   (fresh dest)
#define PK_FMA3_BLO(d, a, bp, c) \
    asm("v_pk_fma_f32 %0, %1, %2, %3 op_sel:[0,0,0] op_sel_hi:[1,0,1]" \
        : "=v"(d) : "v"(a), "v"(bp), "v"(c))
// d = a * broadcast(b.lo)   (fresh dest)
#define PK_MUL_BLO(d, a, bp) \
    asm("v_pk_mul_f32 %0, %1, %2 op_sel:[0,0] op_sel_hi:[1,0]" \
        : "=v"(d) : "v"(a), "v"(bp))

__global__ __launch_bounds__(256, 4) void gru_l2l_kernel(
    const float* __restrict__ hp, const float* __restrict__ gp,
    const float* __restrict__ Wi_r, const float* __restrict__ Wh_r, const float* __restrict__ bh_r,
    const float* __restrict__ Wi_z, const float* __restrict__ Wh_z, const float* __restrict__ bh_z,
    const float* __restrict__ Wi_n, const float* __restrict__ Wh_n, const float* __restrict__ bh_n,
    const float* __restrict__ Wm, const float* __restrict__ bm,
    float* __restrict__ out, int nrows)
{
    const int npairs = nrows << 2;               // h as float2 elements
    const int tid    = blockIdx.x * blockDim.x + threadIdx.x;
    const int stride = blockDim.x * gridDim.x;   // multiple of 4 -> m loop-invariant
    const int m      = tid & 3;                  // column pair owned: {2m, 2m+1}
    const int c0     = m << 1;

    const float L2E = 1.44269504088896341f;      // log2(e)

    // Packed per-lane weights: columns (c0, c0+1). Wi_* [2,8], Wh_* [8,8] row-major.
    // r/z weights+biases pre-scaled by log2e: sigmoid(x) = rcp(1 + exp2(-x*log2e)).
    f32x2 wir0 = { Wi_r[c0] * L2E,     Wi_r[c0 + 1] * L2E };
    f32x2 wir1 = { Wi_r[8 + c0] * L2E, Wi_r[8 + c0 + 1] * L2E };
    f32x2 wiz0 = { Wi_z[c0] * L2E,     Wi_z[c0 + 1] * L2E };
    f32x2 wiz1 = { Wi_z[8 + c0] * L2E, Wi_z[8 + c0 + 1] * L2E };
    f32x2 win0 = { Wi_n[c0],           Wi_n[c0 + 1] };
    f32x2 win1 = { Wi_n[8 + c0],       Wi_n[8 + c0 + 1] };
    f32x2 whr[8], whz[8], whn[8];
#pragma unroll
    for (int k = 0; k < 8; ++k) {
        whr[k] = (f32x2){ Wh_r[k * 8 + c0] * L2E, Wh_r[k * 8 + c0 + 1] * L2E };
        whz[k] = (f32x2){ Wh_z[k * 8 + c0] * L2E, Wh_z[k * 8 + c0 + 1] * L2E };
        whn[k] = (f32x2){ Wh_n[k * 8 + c0],       Wh_n[k * 8 + c0 + 1] };
    }
    f32x2 br = { bh_r[c0] * L2E, bh_r[c0 + 1] * L2E };
    f32x2 bz = { bh_z[c0] * L2E, bh_z[c0 + 1] * L2E };
    f32x2 bn = { bh_n[c0],       bh_n[c0 + 1] };
    float wmx  = Wm[c0], wmy = Wm[c0 + 1];
    float bmv2 = bm[0] * L2E;                    // pre-scaled for final exp2

    PIN(wir0); PIN(wir1); PIN(wiz0); PIN(wiz1); PIN(win0); PIN(win1);
#pragma unroll
    for (int k = 0; k < 8; ++k) { PIN(whr[k]); PIN(whz[k]); PIN(whn[k]); }
    PIN(br); PIN(bz); PIN(bn); PIN(wmx); PIN(wmy); PIN(bmv2);
    asm volatile("" ::: "memory");               // forbid re-loading the weights

    const f32x2* __restrict__ hp2  = (const f32x2*)hp;
    f32x2* __restrict__       out2 = (f32x2*)out;
    float* __restrict__       outo = out + ((long)nrows << 3);  // out scalars follow h_new

    for (int p = tid; p < npairs; p += stride) {
        const int   row = p >> 2;
        f32x2       hv  = hp2[p];                // coalesced dwordx2
        const float g   = gp[row];               // 4 lanes share each address

        // gradient preprocessing (per row, 4x redundant). lg = log(|g|+eps)/10.
        // Branch is continuous at lg==-1 so fast-log flips are safe.
        const float ag = fabsf(g) + 1e-8f;
        const float lg = __builtin_amdgcn_logf(ag) * 0.069314718055994531f;
        f32x2 gin;
        if (lg >= -1.0f) {
            gin.x = lg;
            gin.y = (g > 0.0f) ? 1.0f : -1.0f;   // g != 0 guaranteed in this branch
        } else {
            gin.x = -1.0f;
            gin.y = 22026.465794806718f * g;     // exp(10) * g
        }

        // broadcast the row's 8 h-values across its 4-lane group, pairwise:
        // hb_q = {h[2q], h[2q+1]}. BitMode: src = (lane & 0x1C) | q
        // -> offset = (q<<5) | 0x1C
        f32x2 hb0, hb1, hb2, hb3;
        hb0.x = SWZ(hv.x, 0x01C); hb0.y = SWZ(hv.y, 0x01C);
        hb1.x = SWZ(hv.x, 0x03C); hb1.y = SWZ(hv.y, 0x03C);
        hb2.x = SWZ(hv.x, 0x05C); hb2.y = SWZ(hv.y, 0x05C);
        hb3.x = SWZ(hv.x, 0x07C); hb3.y = SWZ(hv.y, 0x07C);

        f32x2 ar, az, an, hn;
        PK_FMA3_BLO(ar, wir0, gin, br);          // r/z pre-scaled by log2e
        PK_FMA_BHI (ar, wir1, gin);
        PK_FMA3_BLO(az, wiz0, gin, bz);
        PK_FMA_BHI (az, wiz1, gin);
        PK_MUL_BLO (an, win0, gin);              // input dense: no bias
        PK_FMA_BHI (an, win1, gin);
        PK_FMA3_BLO(hn, whn[0], hb0, bn);
        PK_FMA_BLO (ar, whr[0], hb0);
        PK_FMA_BLO (az, whz[0], hb0);
        PK_FMA_BHI (ar, whr[1], hb0);
        PK_FMA_BHI (az, whz[1], hb0);
        PK_FMA_BHI (hn, whn[1], hb0);
#define DOT2(Q, K0, K1) \
        PK_FMA_BLO(ar, whr[K0], hb##Q); \
        PK_FMA_BLO(az, whz[K0], hb##Q); \
        PK_FMA_BLO(hn, whn[K0], hb##Q); \
        PK_FMA_BHI(ar, whr[K1], hb##Q); \
        PK_FMA_BHI(az, whz[K1], hb##Q); \
        PK_FMA_BHI(hn, whn[K1], hb##Q);
        DOT2(1, 2, 3) DOT2(2, 4, 5) DOT2(3, 6, 7)
#undef DOT2

        // sigmoid with pre-scaled input: 1/(1+exp2(-x))  (no packed trans pipe)
        const float rx = __builtin_amdgcn_rcpf(1.0f + __builtin_amdgcn_exp2f(-ar.x));
        const float ry = __builtin_amdgcn_rcpf(1.0f + __builtin_amdgcn_exp2f(-ar.y));
        const float zx = __builtin_amdgcn_rcpf(1.0f + __builtin_amdgcn_exp2f(-az.x));
        const float zy = __builtin_amdgcn_rcpf(1.0f + __builtin_amdgcn_exp2f(-az.y));

        const float prex = fmaf(rx, hn.x, an.x);
        const float prey = fmaf(ry, hn.y, an.y);
        // overflow-safe tanh: t = exp2(-2*log2e*|x|) in [0,1]
        const float tx = __builtin_amdgcn_exp2f(-2.885390081777927f * fabsf(prex));
        const float ty = __builtin_amdgcn_exp2f(-2.885390081777927f * fabsf(prey));
        const float nx = copysignf((1.0f - tx) * __builtin_amdgcn_rcpf(1.0f + tx), prex);
        const float ny = copysignf((1.0f - ty) * __builtin_amdgcn_rcpf(1.0f + ty), prey);
        const float hnx = fmaf(zx, hv.x - nx, nx);   // (1-z)*n + z*h
        const float hny = fmaf(zy, hv.y - ny, ny);
        f32x2 ho; ho.x = hnx; ho.y = hny;
        out2[p] = ho;                            // coalesced dwordx2

        // Dense(1): reduce over the 4-lane group (2-step xor butterfly)
        float s = fmaf(hny, wmy, hnx * wmx);
        s += SWZ(s, 0x041F);   // xor 1
        s += SWZ(s, 0x081F);   // xor 2
        if (m == 0) {
            outo[row] = -__builtin_amdgcn_exp2f(fmaf(s, L2E, bmv2)) * g;
        }
    }
}

extern "C" void kernel_launch(void* const* d_in, const int* in_sizes, int n_in,
                              void* d_out, int out_size, void* d_ws, size_t ws_size,
                              hipStream_t stream) {
    const float* hp   = (const float*)d_in[0];
    const float* gp   = (const float*)d_in[1];
    const float* Wi_r = (const float*)d_in[2];
    const float* Wh_r = (const float*)d_in[3];
    const float* bh_r = (const float*)d_in[4];
    const float* Wi_z = (const float*)d_in[5];
    const float* Wh_z = (const float*)d_in[6];
    const float* bh_z = (const float*)d_in[7];
    const float* Wi_n = (const float*)d_in[8];
    const float* Wh_n = (const float*)d_in[9];
    const float* bh_n = (const float*)d_in[10];
    const float* Wm   = (const float*)d_in[11];
    const float* bm   = (const float*)d_in[12];
    const int nrows   = in_sizes[1];             // N = 8388608

    gru_l2l_kernel<<<8192, 256, 0, stream>>>(hp, gp, Wi_r, Wh_r, bh_r,
                                             Wi_z, Wh_z, bh_z,
                                             Wi_n, Wh_n, bh_n,
                                             Wm, bm, (float*)d_out, nrows);
}

// Round 3
// 558.343 us; speedup vs baseline: 1.0151x; 1.0151x over previous
//
#include <hip/hip_runtime.h>

// L2LGD2: learned-optimizer update step (GRUCell hid=8 + Dense(1) per row).
//
// R6: attack the latency bound R5 exposed. R5 post-mortem: packed FMAs halved
// VALU issue (VALUBusy 74->41%) but dur got WORSE (193->209us) -> the kernel
// became dependency-latency-bound at ~4 waves/SIMD: per iteration one serial
// chain {global load -> 8 ds_swizzle (LDS latency + lgkm waits) -> tied-dest
// packed-FMA chains -> serial transcendentals -> butterfly}.
// Two fixes:
//  (a) DPP quad_perm replaces ALL ds_swizzle. The 4-lane row groups are
//      exactly DPP quads: quad_perm:[q,q,q,q] broadcasts lane q,
//      [1,0,3,2]/[2,3,0,1] are the xor butterflies. LDS pipe drops out of
//      the critical chain entirely (VALU mov, ~2cyc, no lgkmcnt).
//  (b) unroll x2 with BRANCHLESS bodies (gin via v_cndmask, outo stores
//      deferred past both chains) so two independent rows' chains sit in one
//      basic block and the scheduler interleaves them -> 2x ILP vs the
//      ~600-900cyc load latency.
//
// Carried: 4 lanes/row packed-column layout, v_pk_fma_f32 with op_sel
// half-broadcast, __launch_bounds__(256,4), PIN + asm memory barrier pinning
// the ~69 weight VGPRs.

typedef float f32x2 __attribute__((ext_vector_type(2)));

#define PIN(x) asm volatile("" : "+v"(x))

// DPP cross-lane within the 4-lane quad (row group). ctrl is quad_perm code.
#define QP(x, ctrl) __int_as_float(__builtin_amdgcn_mov_dpp(__float_as_int(x), (ctrl), 0xF, 0xF, false))
// broadcast lane q of quad: ctrl = q*0x55
#define QP_B0 0x00
#define QP_B1 0x55
#define QP_B2 0xAA
#define QP_B3 0xFF
#define QP_X1 0xB1   // [1,0,3,2] xor 1
#define QP_X2 0x4E   // [2,3,0,1] xor 2

// d += a * broadcast(b.lo)   [all operands f32x2 register pairs]
#define PK_FMA_BLO(d, a, bp) \
    asm("v_pk_fma_f32 %0, %1, %2, %0 op_sel:[0,0,0] op_sel_hi:[1,0,1]" \
        : "+v"(d) : "v"(a), "v"(bp))
// d += a * broadcast(b.hi)
#define PK_FMA_BHI(d, a, bp) \
    asm("v_pk_fma_f32 %0, %1, %2, %0 op_sel:[0,1,0] op_sel_hi:[1,1,1]" \
        : "+v"(d) : "v"(a), "v"(bp))
// d = a * broadcast(b.lo) + c   (fresh dest)
#define PK_FMA3_BLO(d, a, bp, c) \
    asm("v_pk_fma_f32 %0, %1, %2, %3 op_sel:[0,0,0] op_sel_hi:[1,0,1]" \
        : "=v"(d) : "v"(a), "v"(bp), "v"(c))
// d = a * broadcast(b.lo)   (fresh dest)
#define PK_MUL_BLO(d, a, bp) \
    asm("v_pk_mul_f32 %0, %1, %2 op_sel:[0,0] op_sel_hi:[1,0]" \
        : "=v"(d) : "v"(a), "v"(bp))

__global__ __launch_bounds__(256, 4) void gru_l2l_kernel(
    const float* __restrict__ hp, const float* __restrict__ gp,
    const float* __restrict__ Wi_r, const float* __restrict__ Wh_r, const float* __restrict__ bh_r,
    const float* __restrict__ Wi_z, const float* __restrict__ Wh_z, const float* __restrict__ bh_z,
    const float* __restrict__ Wi_n, const float* __restrict__ Wh_n, const float* __restrict__ bh_n,
    const float* __restrict__ Wm, const float* __restrict__ bm,
    float* __restrict__ out, int nrows)
{
    const int npairs = nrows << 2;               // h as float2 elements
    const int tid    = blockIdx.x * blockDim.x + threadIdx.x;
    const int stride = blockDim.x * gridDim.x;   // multiple of 4 -> m loop-invariant
    const int m      = tid & 3;                  // column pair owned: {2m, 2m+1}
    const int c0     = m << 1;

    const float L2E = 1.44269504088896341f;      // log2(e)

    // Packed per-lane weights: columns (c0, c0+1). Wi_* [2,8], Wh_* [8,8] row-major.
    // r/z weights+biases pre-scaled by log2e: sigmoid(x) = rcp(1 + exp2(-x*log2e)).
    f32x2 wir0 = { Wi_r[c0] * L2E,     Wi_r[c0 + 1] * L2E };
    f32x2 wir1 = { Wi_r[8 + c0] * L2E, Wi_r[8 + c0 + 1] * L2E };
    f32x2 wiz0 = { Wi_z[c0] * L2E,     Wi_z[c0 + 1] * L2E };
    f32x2 wiz1 = { Wi_z[8 + c0] * L2E, Wi_z[8 + c0 + 1] * L2E };
    f32x2 win0 = { Wi_n[c0],           Wi_n[c0 + 1] };
    f32x2 win1 = { Wi_n[8 + c0],       Wi_n[8 + c0 + 1] };
    f32x2 whr[8], whz[8], whn[8];
#pragma unroll
    for (int k = 0; k < 8; ++k) {
        whr[k] = (f32x2){ Wh_r[k * 8 + c0] * L2E, Wh_r[k * 8 + c0 + 1] * L2E };
        whz[k] = (f32x2){ Wh_z[k * 8 + c0] * L2E, Wh_z[k * 8 + c0 + 1] * L2E };
        whn[k] = (f32x2){ Wh_n[k * 8 + c0],       Wh_n[k * 8 + c0 + 1] };
    }
    f32x2 br = { bh_r[c0] * L2E, bh_r[c0 + 1] * L2E };
    f32x2 bz = { bh_z[c0] * L2E, bh_z[c0 + 1] * L2E };
    f32x2 bn = { bh_n[c0],       bh_n[c0 + 1] };
    float wmx  = Wm[c0], wmy = Wm[c0 + 1];
    float bmv2 = bm[0] * L2E;                    // pre-scaled for final exp2

    PIN(wir0); PIN(wir1); PIN(wiz0); PIN(wiz1); PIN(win0); PIN(win1);
#pragma unroll
    for (int k = 0; k < 8; ++k) { PIN(whr[k]); PIN(whz[k]); PIN(whn[k]); }
    PIN(br); PIN(bz); PIN(bn); PIN(wmx); PIN(wmy); PIN(bmv2);
    asm volatile("" ::: "memory");               // forbid re-loading the weights

    const f32x2* __restrict__ hp2  = (const f32x2*)hp;
    f32x2* __restrict__       out2 = (f32x2*)out;
    float* __restrict__       outo = out + ((long)nrows << 3);  // out scalars follow h_new

    // Fully branchless body: computes h_new pair (stored) and returns the
    // quad-reduced Dense(1) pre-activation s (valid in all 4 lanes).
    auto body = [&](const f32x2 hv, const float g, const int p) -> float {
        // gradient preprocessing (per row, 4x redundant). lg = log(|g|+eps)/10.
        // Branch is continuous at lg==-1 so fast-log flips are safe.
        const float ag = fabsf(g) + 1e-8f;
        const float lg = __builtin_amdgcn_logf(ag) * 0.069314718055994531f;
        const bool  hi = (lg >= -1.0f);
        f32x2 gin;
        gin.x = hi ? lg : -1.0f;
        gin.y = hi ? ((g > 0.0f) ? 1.0f : -1.0f)   // g != 0 guaranteed when hi
                   : 22026.465794806718f * g;      // exp(10) * g

        // broadcast the row's 8 h-values across the quad, pairwise (DPP):
        f32x2 hb0, hb1, hb2, hb3;
        hb0.x = QP(hv.x, QP_B0); hb0.y = QP(hv.y, QP_B0);
        hb1.x = QP(hv.x, QP_B1); hb1.y = QP(hv.y, QP_B1);
        hb2.x = QP(hv.x, QP_B2); hb2.y = QP(hv.y, QP_B2);
        hb3.x = QP(hv.x, QP_B3); hb3.y = QP(hv.y, QP_B3);

        f32x2 ar, az, an, hn;
        PK_FMA3_BLO(ar, wir0, gin, br);          // r/z pre-scaled by log2e
        PK_FMA_BHI (ar, wir1, gin);
        PK_FMA3_BLO(az, wiz0, gin, bz);
        PK_FMA_BHI (az, wiz1, gin);
        PK_MUL_BLO (an, win0, gin);              // input dense: no bias
        PK_FMA_BHI (an, win1, gin);
        PK_FMA3_BLO(hn, whn[0], hb0, bn);
        PK_FMA_BLO (ar, whr[0], hb0);
        PK_FMA_BLO (az, whz[0], hb0);
        PK_FMA_BHI (ar, whr[1], hb0);
        PK_FMA_BHI (az, whz[1], hb0);
        PK_FMA_BHI (hn, whn[1], hb0);
#define DOT2(Q, K0, K1) \
        PK_FMA_BLO(ar, whr[K0], hb##Q); \
        PK_FMA_BLO(az, whz[K0], hb##Q); \
        PK_FMA_BLO(hn, whn[K0], hb##Q); \
        PK_FMA_BHI(ar, whr[K1], hb##Q); \
        PK_FMA_BHI(az, whz[K1], hb##Q); \
        PK_FMA_BHI(hn, whn[K1], hb##Q);
        DOT2(1, 2, 3) DOT2(2, 4, 5) DOT2(3, 6, 7)
#undef DOT2

        // sigmoid with pre-scaled input: 1/(1+exp2(-x))  (no packed trans pipe)
        const float rx = __builtin_amdgcn_rcpf(1.0f + __builtin_amdgcn_exp2f(-ar.x));
        const float ry = __builtin_amdgcn_rcpf(1.0f + __builtin_amdgcn_exp2f(-ar.y));
        const float zx = __builtin_amdgcn_rcpf(1.0f + __builtin_amdgcn_exp2f(-az.x));
        const float zy = __builtin_amdgcn_rcpf(1.0f + __builtin_amdgcn_exp2f(-az.y));

        const float prex = fmaf(rx, hn.x, an.x);
        const float prey = fmaf(ry, hn.y, an.y);
        // overflow-safe tanh: t = exp2(-2*log2e*|x|) in [0,1]
        const float tx = __builtin_amdgcn_exp2f(-2.885390081777927f * fabsf(prex));
        const float ty = __builtin_amdgcn_exp2f(-2.885390081777927f * fabsf(prey));
        const float nx = copysignf((1.0f - tx) * __builtin_amdgcn_rcpf(1.0f + tx), prex);
        const float ny = copysignf((1.0f - ty) * __builtin_amdgcn_rcpf(1.0f + ty), prey);
        const float hnx = fmaf(zx, hv.x - nx, nx);   // (1-z)*n + z*h
        const float hny = fmaf(zy, hv.y - ny, ny);
        f32x2 ho; ho.x = hnx; ho.y = hny;
        out2[p] = ho;                            // coalesced dwordx2

        // Dense(1): reduce over the quad (DPP xor butterfly, stays on VALU)
        float s = fmaf(hny, wmy, hnx * wmx);
        s += QP(s, QP_X1);
        s += QP(s, QP_X2);
        return s;
    };

    const int stride2 = stride << 1;
    int p = tid;
    for (; p + stride < npairs; p += stride2) {
        const int pB = p + stride;
        // hoist all loads of both bodies to the top of the (single) block
        const f32x2 hvA = hp2[p];
        const float gA  = gp[p >> 2];
        const f32x2 hvB = hp2[pB];
        const float gB  = gp[pB >> 2];

        const float sA = body(hvA, gA, p);
        const float sB = body(hvB, gB, pB);

        if (m == 0) {                            // one divergent block per trip
            outo[p >> 2]  = -__builtin_amdgcn_exp2f(fmaf(sA, L2E, bmv2)) * gA;
            outo[pB >> 2] = -__builtin_amdgcn_exp2f(fmaf(sB, L2E, bmv2)) * gB;
        }
    }
    if (p < npairs) {                            // tail (absent for N=8M launch)
        const f32x2 hv = hp2[p];
        const float g  = gp[p >> 2];
        const float s  = body(hv, g, p);
        if (m == 0) {
            outo[p >> 2] = -__builtin_amdgcn_exp2f(fmaf(s, L2E, bmv2)) * g;
        }
    }
}

extern "C" void kernel_launch(void* const* d_in, const int* in_sizes, int n_in,
                              void* d_out, int out_size, void* d_ws, size_t ws_size,
                              hipStream_t stream) {
    const float* hp   = (const float*)d_in[0];
    const float* gp   = (const float*)d_in[1];
    const float* Wi_r = (const float*)d_in[2];
    const float* Wh_r = (const float*)d_in[3];
    const float* bh_r = (const float*)d_in[4];
    const float* Wi_z = (const float*)d_in[5];
    const float* Wh_z = (const float*)d_in[6];
    const float* bh_z = (const float*)d_in[7];
    const float* Wi_n = (const float*)d_in[8];
    const float* Wh_n = (const float*)d_in[9];
    const float* bh_n = (const float*)d_in[10];
    const float* Wm   = (const float*)d_in[11];
    const float* bm   = (const float*)d_in[12];
    const int nrows   = in_sizes[1];             // N = 8388608

    gru_l2l_kernel<<<8192, 256, 0, stream>>>(hp, gp, Wi_r, Wh_r, bh_r,
                                             Wi_z, Wh_z, bh_z,
                                             Wi_n, Wh_n, bh_n,
                                             Wm, bm, (float*)d_out, nrows);
}